// Round 4
// baseline (407.100 us; speedup 1.0000x reference)
//
#include <hip/hip_runtime.h>
#include <hip/hip_bf16.h>
#include <math.h>

#define NV   5023
#define N3   15069
#define NB   2048
#define NTIL 79            // ceil(N3/192) column tiles
#define NPAD (NTIL*192)    // 15168 padded B rows

// ---- workspace byte offsets ----
#define WS_JD_B   0          // 2272 floats
#define WS_ATR_B  9216       // 2048*60*4  = 491520
#define WS_PF_B   500736     // 2048*36*4  = 294912 (fp32 pose_feature)
#define WS_AB_B   795648     // 2048*192*2 = 786432 (bf16 A)
#define WS_BB_B   1582080    // 15168*192*2 = 5824512 (bf16 B, n-major, padded)

typedef __attribute__((ext_vector_type(8))) short short8;
typedef __attribute__((ext_vector_type(4))) float floatx4;

// ---------------- zero the Jdirs accumulator region ----------------
__global__ void k_zero(char* ws) {
    int i = blockIdx.x * 256 + threadIdx.x;
    if (i < 2272) ((float*)(ws + WS_JD_B))[i] = 0.f;
}

// ---------------- Jdirs: 126 slices x 40 verts ----------------
__global__ void k_jdirs(const float* __restrict__ Jreg,   // [5][NV]
                        const float* __restrict__ sdirs,  // [NV][450]
                        const float* __restrict__ vt,     // [NV][3]
                        char* __restrict__ ws) {
    int slice = blockIdx.x;        // 0..125
    int start = slice * 40;
    int end   = min(start + 40, NV);
    int t = threadIdx.x;
    int s0 = t, s1 = t + 256;
    float a0[5] = {0,0,0,0,0}, a1[5] = {0,0,0,0,0};
    for (int v = start; v < end; ++v) {
        float w[5];
        #pragma unroll
        for (int j = 0; j < 5; ++j) w[j] = Jreg[j * NV + v];
        float x0 = (s0 < 450) ? sdirs[(size_t)v * 450 + s0]
                 : (s0 < 453 ? vt[v * 3 + (s0 - 450)] : 0.f);
        float x1 = (s1 < 450) ? sdirs[(size_t)v * 450 + s1]
                 : (s1 < 453 ? vt[v * 3 + (s1 - 450)] : 0.f);
        #pragma unroll
        for (int j = 0; j < 5; ++j) { a0[j] += w[j] * x0; a1[j] += w[j] * x1; }
    }
    float* Jd = (float*)(ws + WS_JD_B);
    #pragma unroll
    for (int j = 0; j < 5; ++j) {
        if (s0 < 453) atomicAdd(&Jd[j * 453 + s0], a0[j]);
        if (s1 < 453) atomicAdd(&Jd[j * 453 + s1], a1[j]);
    }
}

// ---------------- per-batch: J GEMV, rodrigues, chain -> pf (fp32), Atr ----------------
// 32 blocks x 64 threads; betas staged in LDS coalesced (stride 151 = conflict-free)
__global__ void k_batch(const float* __restrict__ shp,
                        const float* __restrict__ expn,
                        const float* __restrict__ neck,
                        const float* __restrict__ jaw,
                        const float* __restrict__ eye,
                        char* __restrict__ ws) {
    __shared__ float JdL[2265];
    __shared__ float betasL[64 * 151];
    __shared__ float poseL[64 * 12];
    int t  = threadIdx.x;          // 0..63
    int b0 = blockIdx.x * 64;
    {
        const float* Jd = (const float*)(ws + WS_JD_B);
        for (int i = t; i < 2265; i += 64) JdL[i] = Jd[i];
    }
    for (int i = t; i < 64 * 150; i += 64) {
        int row = i / 150, col = i % 150;
        float v = (col < 100) ? shp[(size_t)(b0 + row) * 100 + col]
                              : expn[(size_t)(b0 + row) * 50 + (col - 100)];
        betasL[row * 151 + col] = v;
    }
    for (int i = t; i < 192; i += 64) poseL[(i/3)*12 + (i%3)]     = neck[(size_t)b0*3 + i];
    for (int i = t; i < 192; i += 64) poseL[(i/3)*12 + 3 + (i%3)] = jaw[(size_t)b0*3 + i];
    for (int i = t; i < 384; i += 64) poseL[(i/6)*12 + 6 + (i%6)] = eye[(size_t)b0*6 + i];
    __syncthreads();

    int b = b0 + t;
    float* pf  = (float*)(ws + WS_PF_B) + (size_t)b * 36;
    float* Atr = (float*)(ws + WS_ATR_B) + (size_t)b * 60;

    float J[15];
    for (int jk = 0; jk < 15; ++jk) J[jk] = JdL[(jk / 3) * 453 + 450 + (jk % 3)];
    for (int l = 0; l < 150; ++l) {
        float be = betasL[t * 151 + l];
        #pragma unroll
        for (int jj = 0; jj < 5; ++jj)
            #pragma unroll
            for (int kk = 0; kk < 3; ++kk)
                J[jj * 3 + kk] += JdL[jj * 453 + kk * 150 + l] * be;
    }

    float R[5][9];
    for (int jj = 0; jj < 5; ++jj) {
        float rx, ry, rz;
        if (jj == 0)      { rx = 0.f; ry = 0.f; rz = 0.f; }
        else { rx = poseL[t*12 + (jj-1)*3 + 0];
               ry = poseL[t*12 + (jj-1)*3 + 1];
               rz = poseL[t*12 + (jj-1)*3 + 2]; }
        float ax = rx + 1e-8f, ay = ry + 1e-8f, az = rz + 1e-8f;
        float angle = sqrtf(ax*ax + ay*ay + az*az);
        float inv = 1.f / angle;
        float ux = rx * inv, uy = ry * inv, uz = rz * inv;
        float c = cosf(angle), s = sinf(angle);
        float K[9] = {0.f, -uz, uy,  uz, 0.f, -ux,  -uy, ux, 0.f};
        float KK[9];
        #pragma unroll
        for (int r = 0; r < 3; ++r)
            #pragma unroll
            for (int cc = 0; cc < 3; ++cc) {
                float a = 0.f;
                #pragma unroll
                for (int m = 0; m < 3; ++m) a += K[r*3+m] * K[m*3+cc];
                KK[r*3+cc] = a;
            }
        #pragma unroll
        for (int e = 0; e < 9; ++e) R[jj][e] = s * K[e] + (1.f - c) * KK[e];
        R[jj][0] += 1.f; R[jj][4] += 1.f; R[jj][8] += 1.f;
    }

    for (int jj = 1; jj < 5; ++jj)
        #pragma unroll
        for (int e = 0; e < 9; ++e)
            pf[(jj-1)*9 + e] = R[jj][e] - ((e == 0 || e == 4 || e == 8) ? 1.f : 0.f);

    float G[5][12];
    #pragma unroll
    for (int r = 0; r < 3; ++r) {
        #pragma unroll
        for (int cc = 0; cc < 3; ++cc) G[0][r*4+cc] = R[0][r*3+cc];
        G[0][r*4+3] = J[r];
    }
    const int par[5] = {-1, 0, 1, 1, 1};
    for (int jj = 1; jj < 5; ++jj) {
        int p = par[jj];
        float rel[3];
        #pragma unroll
        for (int r = 0; r < 3; ++r) rel[r] = J[jj*3+r] - J[p*3+r];
        #pragma unroll
        for (int r = 0; r < 3; ++r) {
            #pragma unroll
            for (int cc = 0; cc < 3; ++cc) {
                float a = 0.f;
                #pragma unroll
                for (int m = 0; m < 3; ++m) a += G[p][r*4+m] * R[jj][m*3+cc];
                G[jj][r*4+cc] = a;
            }
            float tt = G[p][r*4+3];
            #pragma unroll
            for (int m = 0; m < 3; ++m) tt += G[p][r*4+m] * rel[m];
            G[jj][r*4+3] = tt;
        }
    }
    for (int jj = 0; jj < 5; ++jj)
        #pragma unroll
        for (int r = 0; r < 3; ++r) {
            float tc = 0.f;
            #pragma unroll
            for (int m = 0; m < 3; ++m) tc += G[jj][r*4+m] * J[jj*3+m];
            Atr[jj*12 + r*4 + 0] = G[jj][r*4+0];
            Atr[jj*12 + r*4 + 1] = G[jj][r*4+1];
            Atr[jj*12 + r*4 + 2] = G[jj][r*4+2];
            Atr[jj*12 + r*4 + 3] = G[jj][r*4+3] - tc;
        }
}

// ---------------- build bf16 A [2048][192], fully coalesced ----------------
__global__ void k_aconv(const float* __restrict__ shp,
                        const float* __restrict__ expn,
                        char* __restrict__ ws) {
    int idx = blockIdx.x * 256 + threadIdx.x;   // < 2048*192
    int b = idx / 192, k = idx % 192;
    float v;
    if (k < 100)      v = shp[(size_t)b * 100 + k];
    else if (k < 150) v = expn[(size_t)b * 50 + (k - 100)];
    else if (k < 186) v = ((const float*)(ws + WS_PF_B))[(size_t)b * 36 + (k - 150)];
    else              v = 0.f;
    ((__hip_bfloat16*)(ws + WS_AB_B))[idx] = __float2bfloat16(v);
}

// ---------------- build bf16 B [NPAD][192]: coalesced 16B writes ----------------
__global__ void k_bconv(const float* __restrict__ sdirs,  // [N3][150]
                        const float* __restrict__ pdirs,  // [36][N3]
                        char* __restrict__ ws) {
    int idx = blockIdx.x * 256 + threadIdx.x;   // < NPAD*24
    int kg = idx % 24, n = idx / 24;
    int k0 = kg * 8;
    __hip_bfloat16 val[8];
    #pragma unroll
    for (int e = 0; e < 8; ++e) {
        int k = k0 + e;
        float v = 0.f;
        if (n < N3) {
            if (k < 150)      v = sdirs[(size_t)n * 150 + k];
            else if (k < 186) v = pdirs[(size_t)(k - 150) * N3 + n];
        }
        val[e] = __float2bfloat16(v);
    }
    *(int4*)((__hip_bfloat16*)(ws + WS_BB_B) + (size_t)n * 192 + k0) = *(int4*)val;
}

// ---------------- mega: bf16 MFMA GEMM + fused LBS epilogue ----------------
// 256 thr = 4 waves split over columns (wn=wave). M=128 batch x N=192 cols, K=192 (3 chunks of 64).
#define A_OFF  0          // 128 * 136 = 17408
#define B_OFF  17408      // 192 * 136 = 26112 -> 43520
#define S_VT   65         // vtT word stride
#define S_AT   61         // atrS word stride (61 -> conflict-free lane access)
#define VT_T_OFF 0        // 192*65*4 = 49920
#define ATR_OFF  49920    // 64*61*4 = 15616 -> 65536
#define VTQ_OFF  65536    // 192*4 = 768 -> 66304
#define LBS_OFF  66304    // 320*4 = 1280 -> 67584
#define SMEM_BYTES 67584

__global__ __launch_bounds__(256, 2) void k_mega(
        const char* __restrict__ ws,
        const float* __restrict__ vt,     // [N3]
        const float* __restrict__ lbsw,   // [NV][5]
        float* __restrict__ out) {
    __shared__ __align__(16) unsigned char smem[SMEM_BYTES];
    const unsigned char* AbG = (const unsigned char*)ws + WS_AB_B;
    const unsigned char* BbG = (const unsigned char*)ws + WS_BB_B;
    const float* AtrG = (const float*)(ws + WS_ATR_B);

    const int ntile = blockIdx.x;          // 0..78
    const int b0    = blockIdx.y * 128;    // 16 tiles
    const int t     = threadIdx.x;
    const int lane  = t & 63;
    const int wn    = t >> 6;              // wave: column quarter
    const int l15 = lane & 15, quad = lane >> 4;

    floatx4 acc[8][3];
    #pragma unroll
    for (int f = 0; f < 8; ++f)
        #pragma unroll
        for (int g = 0; g < 3; ++g) {
            floatx4 z = {0.f, 0.f, 0.f, 0.f};
            acc[f][g] = z;
        }

    for (int chunk = 0; chunk < 3; ++chunk) {
        __syncthreads();
        // A: 128 rows x 128 B
        #pragma unroll
        for (int i = 0; i < 4; ++i) {
            int flat = i * 256 + t;
            int row = flat >> 3, piece = flat & 7;
            *(float4*)(smem + A_OFF + row * 136 + piece * 16) =
                *(const float4*)(AbG + (size_t)(b0 + row) * 384 + chunk * 128 + piece * 16);
        }
        // B: 192 rows x 128 B
        #pragma unroll
        for (int i = 0; i < 6; ++i) {
            int flat = i * 256 + t;
            int row = flat >> 3, piece = flat & 7;
            *(float4*)(smem + B_OFF + row * 136 + piece * 16) =
                *(const float4*)(BbG + (size_t)(ntile * 192 + row) * 384 + chunk * 128 + piece * 16);
        }
        __syncthreads();
        #pragma unroll
        for (int ks = 0; ks < 2; ++ks) {
            short8 af[8];
            #pragma unroll
            for (int f = 0; f < 8; ++f)
                af[f] = *(const short8*)(smem + A_OFF + (f * 16 + l15) * 136 + ks * 64 + quad * 16);
            #pragma unroll
            for (int g = 0; g < 3; ++g) {
                short8 bf = *(const short8*)(smem + B_OFF + (wn * 48 + g * 16 + l15) * 136 + ks * 64 + quad * 16);
                #pragma unroll
                for (int f = 0; f < 8; ++f)
                    acc[f][g] = __builtin_amdgcn_mfma_f32_16x16x32_bf16(af[f], bf, acc[f][g], 0, 0, 0);
            }
        }
    }
    __syncthreads();

    float* vtT  = (float*)(smem + VT_T_OFF);   // [192 cols][65]
    float* atrS = (float*)(smem + ATR_OFF);    // [64][61]
    float* vtQ  = (float*)(smem + VTQ_OFF);    // [192]
    float* lbsS = (float*)(smem + LBS_OFF);    // [64][5]

    // stage per-vertex constants once (region disjoint from A/B and vtT/atrS)
    if (t < 192) { int n = ntile * 192 + t; vtQ[t] = (n < N3) ? vt[n] : 0.f; }
    for (int i = t; i < 320; i += 256) {
        int v = ntile * 64 + i / 5;
        lbsS[i] = (v < NV) ? lbsw[(size_t)v * 5 + (i % 5)] : 0.f;
    }

    for (int half = 0; half < 2; ++half) {
        __syncthreads();
        // dump acc rows [half*64, half*64+64) -> vtT[col][rl]
        #pragma unroll
        for (int ff = 0; ff < 4; ++ff) {
            int f = half * 4 + ff;
            #pragma unroll
            for (int g = 0; g < 3; ++g) {
                int col = wn * 48 + g * 16 + l15;
                int rl  = ff * 16 + quad * 4;
                #pragma unroll
                for (int r = 0; r < 4; ++r)
                    vtT[col * S_VT + rl + r] = acc[f][g][r];
            }
        }
        for (int i = t; i < 3840; i += 256) {
            int r = i / 60, j = i % 60;
            atrS[r * S_AT + j] = AtrG[(size_t)(b0 + half * 64) * 60 + i];
        }
        __syncthreads();

        // LBS: lane rl = t&63 (batch row), vgrp = t>>6 (16 verts)
        {
            int rl = t & 63;
            int vgrp = t >> 6;
            float ar[60];
            #pragma unroll
            for (int i = 0; i < 60; ++i) ar[i] = atrS[rl * S_AT + i];
            for (int vv = 0; vv < 16; ++vv) {
                int vloc = vgrp * 16 + vv;
                int c0 = vloc * 3;
                float w0 = lbsS[vloc*5+0], w1 = lbsS[vloc*5+1], w2 = lbsS[vloc*5+2],
                      w3 = lbsS[vloc*5+3], w4 = lbsS[vloc*5+4];
                float px = vtT[(c0+0) * S_VT + rl] + vtQ[c0+0];
                float py = vtT[(c0+1) * S_VT + rl] + vtQ[c0+1];
                float pz = vtT[(c0+2) * S_VT + rl] + vtQ[c0+2];
                float y[3];
                #pragma unroll
                for (int r = 0; r < 3; ++r) {
                    float t0 = w0*ar[ 0+r*4+0] + w1*ar[12+r*4+0] + w2*ar[24+r*4+0]
                             + w3*ar[36+r*4+0] + w4*ar[48+r*4+0];
                    float t1 = w0*ar[ 0+r*4+1] + w1*ar[12+r*4+1] + w2*ar[24+r*4+1]
                             + w3*ar[36+r*4+1] + w4*ar[48+r*4+1];
                    float t2 = w0*ar[ 0+r*4+2] + w1*ar[12+r*4+2] + w2*ar[24+r*4+2]
                             + w3*ar[36+r*4+2] + w4*ar[48+r*4+2];
                    float t3 = w0*ar[ 0+r*4+3] + w1*ar[12+r*4+3] + w2*ar[24+r*4+3]
                             + w3*ar[36+r*4+3] + w4*ar[48+r*4+3];
                    y[r] = t0*px + t1*py + t2*pz + t3;
                }
                vtT[(c0+0) * S_VT + rl] = y[0];
                vtT[(c0+1) * S_VT + rl] = y[1];
                vtT[(c0+2) * S_VT + rl] = y[2];
            }
        }
        __syncthreads();
        // gather from transposed LDS -> coalesced dwordx4 stores (16 B/lane)
        for (int idx = t; idx < 64 * 48; idx += 256) {
            int row = idx / 48, c4 = idx % 48;
            float4 val;
            val.x = vtT[(c4*4+0) * S_VT + row];
            val.y = vtT[(c4*4+1) * S_VT + row];
            val.z = vtT[(c4*4+2) * S_VT + row];
            val.w = vtT[(c4*4+3) * S_VT + row];
            int n = ntile * 192 + c4 * 4;
            size_t ob = (size_t)(b0 + half * 64 + row) * N3 + n;
            if (n + 4 <= N3) {
                *(float4*)&out[ob] = val;
            } else if (n < N3) {
                const float* vs = (const float*)&val;
                for (int e = 0; e < 4; ++e) if (n + e < N3) out[ob + e] = vs[e];
            }
        }
    }
}

extern "C" void kernel_launch(void* const* d_in, const int* in_sizes, int n_in,
                              void* d_out, int out_size, void* d_ws, size_t ws_size,
                              hipStream_t stream) {
    const float* shp  = (const float*)d_in[0];
    const float* expn = (const float*)d_in[1];
    const float* neck = (const float*)d_in[2];
    const float* jaw  = (const float*)d_in[3];
    const float* eye  = (const float*)d_in[4];
    const float* vt   = (const float*)d_in[5];
    const float* sdir = (const float*)d_in[6];
    const float* pdir = (const float*)d_in[7];
    const float* jreg = (const float*)d_in[8];
    const float* lbsw = (const float*)d_in[9];
    char* ws  = (char*)d_ws;
    float* out = (float*)d_out;

    k_zero <<<9,   256, 0, stream>>>(ws);
    k_jdirs<<<126, 256, 0, stream>>>(jreg, sdir, vt, ws);
    k_batch<<<32,  64,  0, stream>>>(shp, expn, neck, jaw, eye, ws);
    k_aconv<<<1536, 256, 0, stream>>>(shp, expn, ws);
    k_bconv<<<1422, 256, 0, stream>>>(sdir, pdir, ws);
    k_mega <<<dim3(NTIL, 16), 256, 0, stream>>>(ws, vt, lbsw, out);
}